// Round 8
// baseline (213.005 us; speedup 1.0000x reference)
//
#include <hip/hip_runtime.h>

#define BATCH 16

// ---------------------------------------------------------------------------
// 16-lane fused d+i unit: one group computes one i-patch output, recomputing
// the d-transform of its 4 input cells on the fly (4 lanes per cell).
// ---------------------------------------------------------------------------
template <int H>
__device__ __forceinline__ float fused_di_unit(
    const float* __restrict__ xb, int p, int j,
    const float* __restrict__ dA, const float* __restrict__ dv,
    const float* __restrict__ dw,
    const float* __restrict__ iA, const float* __restrict__ iv,
    const float* __restrict__ iw) {
  constexpr int NH = (H - 2) / 2;
  constexpr int W2 = H / 2;
  int pi = p / W2, pj = p % W2;
  int sg = j >> 2, j4 = j & 3;
  int r = 2 * pi + (sg >> 1), c = 2 * pj + (sg & 1);
  float tcell;
  bool border = (r == 0) | (r == H - 1) | (c == 0) | (c == H - 1);
  if (border) {
    tcell = xb[r * H + c];  // d leaves borders untouched
  } else {
    int dpi = (r - 1) >> 1, dpj = (c - 1) >> 1;
    int sd = ((r - 1) & 1) * 2 + ((c - 1) & 1);
    int dp = dpi * NH + dpj;
    int R0 = 1 + 2 * dpi, C0 = 1 + 2 * dpj;
    float tin = xb[(R0 + (j4 >> 1)) * H + (C0 + (j4 & 1))];
    const float* Ap = dA + dp * 128;  // [s][f][4][4]
    float vec = dv[dp * 4 + j4];
#pragma unroll
    for (int s = 0; s < 4; s++) {
      float ts = __shfl(tin, s, 4);
      const float* A0 = Ap + s * 32;
      float q0 = 0.f, q1 = 0.f;
#pragma unroll
      for (int i = 0; i < 4; i++) {
        float sv = __shfl(vec, i, 4);
        q0 = fmaf(sv, A0[i * 4 + j4], q0);
        q1 = fmaf(sv, A0[16 + i * 4 + j4], q1);
      }
      vec = ts * q0 + (1.0f - ts) * q1;
    }
    float y = 0.f;
#pragma unroll
    for (int i = 0; i < 4; i++)
      y = fmaf(__shfl(vec, i, 4), dw[dp * 16 + i * 4 + j4], y);
    y = fmaxf(y, 0.0f);
    tcell = __shfl(y, sd, 4);  // the d-output cell this i-cell needs
  }
  // broadcast the 4 cell values to all 16 lanes
  float t[4];
  t[0] = __shfl(tcell, 0, 16);
  t[1] = __shfl(tcell, 4, 16);
  t[2] = __shfl(tcell, 8, 16);
  t[3] = __shfl(tcell, 12, 16);
  // i-MPS (D=16), lane j owns component j
  const float* Ap = iA + p * 2048;  // [s][f][16][16]
  float vec = iv[p * 16 + j];
#pragma unroll
  for (int s = 0; s < 4; s++) {
    const float* A0 = Ap + s * 512;
    float q0 = 0.f, q1 = 0.f;
#pragma unroll
    for (int i = 0; i < 16; i++) {
      float sv = __shfl(vec, i, 16);
      q0 = fmaf(sv, A0[i * 16 + j], q0);
      q1 = fmaf(sv, A0[256 + i * 16 + j], q1);
    }
    vec = t[s] * q0 + (1.0f - t[s]) * q1;
  }
  float partial = vec * iw[p * 16 + j];
#pragma unroll
  for (int off = 8; off >= 1; off >>= 1)
    partial += __shfl_xor(partial, off, 16);
  return fmaxf(partial, 0.0f);
}

// ---------------------------------------------------------------------------
// One fused level. Block 256 = 16 b x 16 j of ONE p (p = blockIdx).
// Levels 1-4: H = 128, 64, 32, 16.
// ---------------------------------------------------------------------------
template <int H>
__global__ __launch_bounds__(256) void level_kernel(
    const float* __restrict__ xin, float* __restrict__ hn,
    const float* __restrict__ dA, const float* __restrict__ dv,
    const float* __restrict__ dw, const float* __restrict__ iA,
    const float* __restrict__ iv, const float* __restrict__ iw) {
  constexpr int W2 = H / 2;
  int g = blockIdx.x * 256 + threadIdx.x;
  int j = g & 15;
  int b = (g >> 4) & 15;
  int p = g >> 8;
  const float* xb = xin + b * H * H;
  float o = fused_di_unit<H>(xb, p, j, dA, dv, dw, iA, iv, iw);
  if (j == 0) hn[b * W2 * W2 + p] = o;
}

// ---------------------------------------------------------------------------
// Tail2: levels 5-6 + final head. One WG (256 thr) per batch element.
// Patch order is ROTATED per WG (p = (u + b) & mask) so the 16 WGs cold-miss
// 16 different patches' params in parallel instead of drafting behind WG0's
// serial cold-fetch chain.
// ---------------------------------------------------------------------------
struct Tail2Args {
  const float* h4;      // 16 x 8 x 8
  const float* in[15];  // d5A..fw  (d_in[25..39])
  float* out;
};

__global__ __launch_bounds__(256) void tail2_kernel(Tail2Args a) {
  __shared__ float x5[64];  // 8x8
  __shared__ float h5[16];  // 4x4
  __shared__ float h6[4];   // 2x2
  int b = blockIdx.x;
  int tid = threadIdx.x;
  if (tid < 16)
    ((float4*)x5)[tid] = ((const float4*)(a.h4 + b * 64))[tid];
  __syncthreads();
  // level 5: H=8 -> 16 units x 16 lanes = 256 threads, rotated patch order
  {
    int j = tid & 15, u = tid >> 4;
    int p = (u + b) & 15;
    float o = fused_di_unit<8>(x5, p, j, a.in[0], a.in[1], a.in[2],
                               a.in[3], a.in[4], a.in[5]);
    if (j == 0) h5[p] = o;
  }
  __syncthreads();
  // level 6: H=4 -> 4 units x 16 lanes = 64 threads, rotated patch order
  if (tid < 64) {
    int j = tid & 15, u = tid >> 4;
    int p = (u + b) & 3;
    float o = fused_di_unit<4>(h5, p, j, a.in[6], a.in[7], a.in[8],
                               a.in[9], a.in[10], a.in[11]);
    if (j == 0) h6[p] = o;
  }
  __syncthreads();
  // final head: flat (2x2) -> 10 classes; 16 lanes, lane j owns vec[j]
  if (tid < 16) {
    int j = tid;
    const float* fA = a.in[12];
    const float* fv = a.in[13];
    const float* fw = a.in[14];
    float t[4] = {h6[0], h6[1], h6[2], h6[3]};
    float vec = fv[j];
#pragma unroll
    for (int s = 0; s < 4; s++) {
      const float* A0 = fA + s * 512;
      float q0 = 0.f, q1 = 0.f;
#pragma unroll
      for (int i = 0; i < 16; i++) {
        float sv = __shfl(vec, i, 16);
        q0 = fmaf(sv, A0[i * 16 + j], q0);
        q1 = fmaf(sv, A0[256 + i * 16 + j], q1);
      }
      vec = t[s] * q0 + (1.0f - t[s]) * q1;
    }
    float acc = 0.0f;
#pragma unroll
    for (int i = 0; i < 16; i++) {
      float sv = __shfl(vec, i, 16);
      float wv = (j < 10) ? fw[i * 10 + j] : 0.0f;
      acc = fmaf(sv, wv, acc);
    }
    if (j < 10) a.out[b * 10 + j] = fmaxf(acc, 0.0f);
  }
}

extern "C" void kernel_launch(void* const* d_in, const int* in_sizes, int n_in,
                              void* d_out, int out_size, void* d_ws, size_t ws_size,
                              hipStream_t stream) {
  const float* x = (const float*)d_in[0];
  float* ws = (float*)d_ws;
  float* h1 = ws;            // 16*64*64 = 65536
  float* h2 = h1 + 65536;    // 16*32*32 = 16384
  float* h3 = h2 + 16384;    // 16*16*16 = 4096
  float* h4 = h3 + 4096;     // 16*8*8   = 1024

  // blocks = W2*W2 (one patch per block, 16 b x 16 j lanes)
  level_kernel<128><<<4096, 256, 0, stream>>>(
      x, h1, (const float*)d_in[1], (const float*)d_in[2],
      (const float*)d_in[3], (const float*)d_in[4], (const float*)d_in[5],
      (const float*)d_in[6]);
  level_kernel<64><<<1024, 256, 0, stream>>>(
      h1, h2, (const float*)d_in[7], (const float*)d_in[8],
      (const float*)d_in[9], (const float*)d_in[10], (const float*)d_in[11],
      (const float*)d_in[12]);
  level_kernel<32><<<256, 256, 0, stream>>>(
      h2, h3, (const float*)d_in[13], (const float*)d_in[14],
      (const float*)d_in[15], (const float*)d_in[16], (const float*)d_in[17],
      (const float*)d_in[18]);
  level_kernel<16><<<64, 256, 0, stream>>>(
      h3, h4, (const float*)d_in[19], (const float*)d_in[20],
      (const float*)d_in[21], (const float*)d_in[22], (const float*)d_in[23],
      (const float*)d_in[24]);

  Tail2Args ta;
  ta.h4 = h4;
  for (int i = 0; i < 15; i++) ta.in[i] = (const float*)d_in[25 + i];
  ta.out = (float*)d_out;
  tail2_kernel<<<BATCH, 256, 0, stream>>>(ta);
}